// Round 2
// baseline (374.925 us; speedup 1.0000x reference)
//
#include <hip/hip_runtime.h>
#include <math.h>

// ChannelDropout: out[b,c,t] = x[b,c,t] * scale[b,c]
// scale = (valid && dist(pos, center0) > 0.1) ? 1/(prob_kept + 1e-8) : 0
// prob_kept = mean over centers 1..N-1 of (dist > 0.1)
// valid = !(pos == (-2,-2))
//
// v3 (two-phase): v2 showed the fused kernel stuck at ~2.5-3.4 TB/s while
// fillBuffer hits 6.6 TB/s — the per-row serial scale chain (pos load ->
// MC loop -> 6-deep shfl tree) sat inline with the stream, and 17600
// one-shot blocks churned (~0.6 us of work each). Split:
//   A) cd_scales: one wave per row -> scale[row] in d_ws (70 KB, ~5 us)
//   B) cd_apply: 2048 long-lived blocks (8/CU co-resident), block-stride
//      over rows; per row one uniform scalar load of scale[row] then a
//      pure float4 load->mul->store stream — the copy-ubench shape.

typedef float f32x4 __attribute__((ext_vector_type(4)));

__global__ __launch_bounds__(256) void ChannelDropout_scales_kernel(
    const float* __restrict__ pos,
    const float* __restrict__ centers,
    float* __restrict__ scale,
    int rows, int ncenters)
{
    const int wid  = (int)((blockIdx.x * 256u + threadIdx.x) >> 6); // global wave = row
    const int lane = threadIdx.x & 63;
    if (wid >= rows) return;

    const float px = pos[2 * wid];
    const float py = pos[2 * wid + 1];
    const bool valid = !(px == -2.0f && py == -2.0f);

    // Monte-Carlo keep count over centers 1..ncenters-1, lane-parallel
    float cnt = 0.0f;
    for (int c = 1 + lane; c < ncenters; c += 64) {
        const float dx = px - centers[2 * c];
        const float dy = py - centers[2 * c + 1];
        // match np: d = sqrt(dx*dx + dy*dy), no fma contraction
        const float d2 = __fadd_rn(__fmul_rn(dx, dx), __fmul_rn(dy, dy));
        cnt += (sqrtf(d2) > 0.1f) ? 1.0f : 0.0f;
    }
    #pragma unroll
    for (int off = 32; off > 0; off >>= 1)
        cnt += __shfl_xor(cnt, off, 64);

    if (lane == 0) {
        const float dx0 = px - centers[0];
        const float dy0 = py - centers[1];
        const float d02 = __fadd_rn(__fmul_rn(dx0, dx0), __fmul_rn(dy0, dy0));
        const bool kept0 = sqrtf(d02) > 0.1f;
        const int denom = (ncenters > 1) ? (ncenters - 1) : 1;
        const float prob = cnt / (float)denom;
        scale[wid] = (valid && kept0) ? (1.0f / (prob + 1e-8f)) : 0.0f;
    }
}

__global__ __launch_bounds__(256) void ChannelDropout_apply_kernel(
    const float* __restrict__ x,
    const float* __restrict__ scale,
    float* __restrict__ out,
    int rows, int tlen)
{
    const int tid = threadIdx.x;
    const int t4  = tlen >> 2;              // 750 float4 per row
    for (int row = blockIdx.x; row < rows; row += gridDim.x) {
        const float s = scale[row];         // uniform -> scalar load, L2-hot
        const size_t base = (size_t)row * (size_t)tlen;
        const f32x4* __restrict__ xr   = (const f32x4*)(x + base);
        f32x4* __restrict__       orow = (f32x4*)(out + base);
        for (int i = tid; i < t4; i += 256) {
            f32x4 v = xr[i];
            __builtin_nontemporal_store(v * s, orow + i);
        }
        for (int i = (t4 << 2) + tid; i < tlen; i += 256) {  // tail (not taken @3000)
            out[base + i] = x[base + i] * s;
        }
    }
}

// Fallback (ws too small): v1-style fused kernel, correctness-safe.
__global__ __launch_bounds__(256) void ChannelDropout_fused_kernel(
    const float* __restrict__ x,
    const float* __restrict__ pos,
    const float* __restrict__ centers,
    float* __restrict__ out,
    int ncenters, int tlen)
{
    const int row  = blockIdx.x;
    const int tid  = threadIdx.x;
    const int lane = tid & 63;

    const float px = pos[2 * row];
    const float py = pos[2 * row + 1];
    const bool valid = !(px == -2.0f && py == -2.0f);
    float cnt = 0.0f;
    for (int c = 1 + lane; c < ncenters; c += 64) {
        const float dx = px - centers[2 * c];
        const float dy = py - centers[2 * c + 1];
        const float d2 = __fadd_rn(__fmul_rn(dx, dx), __fmul_rn(dy, dy));
        cnt += (sqrtf(d2) > 0.1f) ? 1.0f : 0.0f;
    }
    #pragma unroll
    for (int off = 32; off > 0; off >>= 1)
        cnt += __shfl_xor(cnt, off, 64);
    const float dx0 = px - centers[0];
    const float dy0 = py - centers[1];
    const float d02 = __fadd_rn(__fmul_rn(dx0, dx0), __fmul_rn(dy0, dy0));
    const bool kept0 = sqrtf(d02) > 0.1f;
    const int denom = (ncenters > 1) ? (ncenters - 1) : 1;
    const float prob = cnt / (float)denom;
    const float s = (valid && kept0) ? (1.0f / (prob + 1e-8f)) : 0.0f;

    const size_t base = (size_t)row * (size_t)tlen;
    const int t4 = tlen >> 2;
    const f32x4* __restrict__ xr   = (const f32x4*)(x + base);
    f32x4* __restrict__       orow = (f32x4*)(out + base);
    for (int i = tid; i < t4; i += 256) {
        f32x4 v = xr[i];
        __builtin_nontemporal_store(v * s, orow + i);
    }
    for (int i = (t4 << 2) + tid; i < tlen; i += 256)
        out[base + i] = x[base + i] * s;
}

extern "C" void kernel_launch(void* const* d_in, const int* in_sizes, int n_in,
                              void* d_out, int out_size, void* d_ws, size_t ws_size,
                              hipStream_t stream) {
    const float* x       = (const float*)d_in[0];   // [B, C, T]
    const float* pos     = (const float*)d_in[1];   // [B, C, 2]
    const float* centers = (const float*)d_in[2];   // [N, 2]
    float* out = (float*)d_out;

    const int rows     = in_sizes[1] / 2;       // B*C = 17600
    const int tlen     = in_sizes[0] / rows;    // T = 3000
    const int ncenters = in_sizes[2] / 2;       // 101

    if (d_ws != nullptr && ws_size >= (size_t)rows * sizeof(float)) {
        float* scale = (float*)d_ws;
        const int ablocks = (rows + 3) / 4;     // 4 waves (rows) per block
        ChannelDropout_scales_kernel<<<ablocks, 256, 0, stream>>>(
            pos, centers, scale, rows, ncenters);
        const int bblocks = 2048;               // 8/CU, fully co-resident
        ChannelDropout_apply_kernel<<<bblocks, 256, 0, stream>>>(
            x, scale, out, rows, tlen);
    } else {
        ChannelDropout_fused_kernel<<<rows, 256, 0, stream>>>(
            x, pos, centers, out, ncenters, tlen);
    }
}

// Round 5
// 370.389 us; speedup vs baseline: 1.0122x; 1.0122x over previous
//
#include <hip/hip_runtime.h>
#include <math.h>

// ChannelDropout: out[b,c,t] = x[b,c,t] * scale[b,c]
// scale = (valid && dist(pos, center0) > 0.1) ? 1/(prob_kept + 1e-8) : 0
// prob_kept = mean over centers 1..N-1 of (dist > 0.1)
// valid = !(pos == (-2,-2))
//
// v4 (2nd resubmit — rounds 3 & 4 died to MI355X container-acquisition
// failures; source audited twice for OOB/overflow/hang/graph-capture
// hazards: none. The experiment has never executed.)
// Bench-total reconstruction: ~256 us of harness poison-fills + kernel.
// v1 fused ~95 us; nt stores cost ~8 us; v3 row-loop apply ~114 us.
// This version makes apply EXACTLY the m13 copy-ubench shape:
//   - flat grid-stride over all float4 of x (no row-granular blocks)
//   - 2048 blocks x 256 thr = 32 waves/CU, one generation, even work
//   - 4-deep manual unroll -> 8 loads in flight per wave
//   - PLAIN stores (write-combine through L2; nt was a regression)
//   - row = (i4 * magic) >> 40 (host-computed, exactness-guarded);
//     scale[row] is an L1-broadcast vector load, no scalar-load chain
// Scales precomputed into d_ws by a one-wave-per-row kernel (~5 us).

typedef float f32x4 __attribute__((ext_vector_type(4)));

__global__ __launch_bounds__(256) void ChannelDropout_scales_kernel(
    const float* __restrict__ pos,
    const float* __restrict__ centers,
    float* __restrict__ scale,
    int rows, int ncenters)
{
    const int wid  = (int)((blockIdx.x * 256u + threadIdx.x) >> 6); // wave = row
    const int lane = threadIdx.x & 63;
    if (wid >= rows) return;

    const float px = pos[2 * wid];
    const float py = pos[2 * wid + 1];
    const bool valid = !(px == -2.0f && py == -2.0f);

    float cnt = 0.0f;
    for (int c = 1 + lane; c < ncenters; c += 64) {
        const float dx = px - centers[2 * c];
        const float dy = py - centers[2 * c + 1];
        // match np: d = sqrt(dx*dx + dy*dy), no fma contraction
        const float d2 = __fadd_rn(__fmul_rn(dx, dx), __fmul_rn(dy, dy));
        cnt += (sqrtf(d2) > 0.1f) ? 1.0f : 0.0f;
    }
    #pragma unroll
    for (int off = 32; off > 0; off >>= 1)
        cnt += __shfl_xor(cnt, off, 64);

    if (lane == 0) {
        const float dx0 = px - centers[0];
        const float dy0 = py - centers[1];
        const float d02 = __fadd_rn(__fmul_rn(dx0, dx0), __fmul_rn(dy0, dy0));
        const bool kept0 = sqrtf(d02) > 0.1f;
        const int denom = (ncenters > 1) ? (ncenters - 1) : 1;
        const float prob = cnt / (float)denom;
        scale[wid] = (valid && kept0) ? (1.0f / (prob + 1e-8f)) : 0.0f;
    }
}

// Flat scaled copy: i4 -> row via magic divide (exactness host-guarded).
// Plain stores, 4-deep unroll.
__global__ __launch_bounds__(256) void ChannelDropout_apply_flat(
    const float* __restrict__ x,
    const float* __restrict__ scale,
    float* __restrict__ out,
    int n4, unsigned long long magic)
{
    const f32x4* __restrict__ x4 = (const f32x4*)x;
    f32x4* __restrict__       o4 = (f32x4*)out;
    const int nt = (int)(gridDim.x * blockDim.x);   // 524288
    int i = (int)(blockIdx.x * blockDim.x + threadIdx.x);

    for (; i + 3 * nt < n4; i += 4 * nt) {
        const int i0 = i, i1 = i + nt, i2 = i + 2 * nt, i3 = i + 3 * nt;
        const f32x4 v0 = x4[i0];
        const f32x4 v1 = x4[i1];
        const f32x4 v2 = x4[i2];
        const f32x4 v3 = x4[i3];
        const float s0 = scale[(int)(((unsigned long long)(unsigned)i0 * magic) >> 40)];
        const float s1 = scale[(int)(((unsigned long long)(unsigned)i1 * magic) >> 40)];
        const float s2 = scale[(int)(((unsigned long long)(unsigned)i2 * magic) >> 40)];
        const float s3 = scale[(int)(((unsigned long long)(unsigned)i3 * magic) >> 40)];
        o4[i0] = v0 * s0;
        o4[i1] = v1 * s1;
        o4[i2] = v2 * s2;
        o4[i3] = v3 * s3;
    }
    for (; i < n4; i += nt) {
        const float s = scale[(int)(((unsigned long long)(unsigned)i * magic) >> 40)];
        o4[i] = x4[i] * s;
    }
}

// Generic fallback (odd tlen or magic guard fails): scalar flat copy.
__global__ __launch_bounds__(256) void ChannelDropout_apply_scalar(
    const float* __restrict__ x,
    const float* __restrict__ scale,
    float* __restrict__ out,
    long long n, int tlen)
{
    const long long nt = (long long)gridDim.x * blockDim.x;
    for (long long i = (long long)blockIdx.x * blockDim.x + threadIdx.x;
         i < n; i += nt) {
        out[i] = x[i] * scale[(int)(i / tlen)];
    }
}

// Fallback (no workspace): v1-style fused kernel, plain stores.
__global__ __launch_bounds__(256) void ChannelDropout_fused_kernel(
    const float* __restrict__ x,
    const float* __restrict__ pos,
    const float* __restrict__ centers,
    float* __restrict__ out,
    int ncenters, int tlen)
{
    const int row  = blockIdx.x;
    const int tid  = threadIdx.x;
    const int lane = tid & 63;

    const float px = pos[2 * row];
    const float py = pos[2 * row + 1];
    const bool valid = !(px == -2.0f && py == -2.0f);
    float cnt = 0.0f;
    for (int c = 1 + lane; c < ncenters; c += 64) {
        const float dx = px - centers[2 * c];
        const float dy = py - centers[2 * c + 1];
        const float d2 = __fadd_rn(__fmul_rn(dx, dx), __fmul_rn(dy, dy));
        cnt += (sqrtf(d2) > 0.1f) ? 1.0f : 0.0f;
    }
    #pragma unroll
    for (int off = 32; off > 0; off >>= 1)
        cnt += __shfl_xor(cnt, off, 64);
    const float dx0 = px - centers[0];
    const float dy0 = py - centers[1];
    const float d02 = __fadd_rn(__fmul_rn(dx0, dx0), __fmul_rn(dy0, dy0));
    const bool kept0 = sqrtf(d02) > 0.1f;
    const int denom = (ncenters > 1) ? (ncenters - 1) : 1;
    const float prob = cnt / (float)denom;
    const float s = (valid && kept0) ? (1.0f / (prob + 1e-8f)) : 0.0f;

    const size_t base = (size_t)row * (size_t)tlen;
    const int t4 = tlen >> 2;
    const f32x4* __restrict__ xr   = (const f32x4*)(x + base);
    f32x4* __restrict__       orow = (f32x4*)(out + base);
    for (int i = tid; i < t4; i += 256) {
        f32x4 v = xr[i];
        orow[i] = v * s;
    }
    for (int i = (t4 << 2) + tid; i < tlen; i += 256)
        out[base + i] = x[base + i] * s;
}

extern "C" void kernel_launch(void* const* d_in, const int* in_sizes, int n_in,
                              void* d_out, int out_size, void* d_ws, size_t ws_size,
                              hipStream_t stream) {
    const float* x       = (const float*)d_in[0];   // [B, C, T]
    const float* pos     = (const float*)d_in[1];   // [B, C, 2]
    const float* centers = (const float*)d_in[2];   // [N, 2]
    float* out = (float*)d_out;

    const int rows     = in_sizes[1] / 2;       // B*C = 17600
    const int tlen     = in_sizes[0] / rows;    // T = 3000
    const int ncenters = in_sizes[2] / 2;       // 101
    if (rows <= 0 || tlen <= 0) return;

    if (d_ws != nullptr && ws_size >= (size_t)rows * sizeof(float)) {
        float* scale = (float*)d_ws;
        const int ablocks = (rows + 3) / 4;     // 4 waves (rows) per block
        ChannelDropout_scales_kernel<<<ablocks, 256, 0, stream>>>(
            pos, centers, scale, rows, ncenters);

        const int bblocks = 2048;               // 32 waves/CU, one generation
        if ((tlen & 3) == 0) {
            const int t4r = tlen >> 2;          // 750 float4 per row
            const long long n4 = (long long)rows * t4r;   // 13.2M
            // magic divide by t4r: row = (i*magic) >> 40; exact iff
            // err*i_max < 2^40 (err = t4r*magic - 2^40 <= t4r) and the
            // u64 product can't overflow.
            const unsigned long long magic = (0x10000000000ULL / (unsigned)t4r) + 1ULL;
            const bool magic_ok =
                (double)t4r * (double)n4 < 1.0e12 &&      // exactness
                (double)n4 * (double)magic < 1.8e19;      // u64 product
            if (magic_ok && n4 < 2147000000LL) {
                ChannelDropout_apply_flat<<<bblocks, 256, 0, stream>>>(
                    x, scale, out, (int)n4, magic);
                return;
            }
        }
        const long long n = (long long)rows * tlen;
        ChannelDropout_apply_scalar<<<bblocks, 256, 0, stream>>>(
            x, scale, out, n, tlen);
    } else {
        ChannelDropout_fused_kernel<<<rows, 256, 0, stream>>>(
            x, pos, centers, out, ncenters, tlen);
    }
}

// Round 6
// 349.246 us; speedup vs baseline: 1.0735x; 1.0605x over previous
//
#include <hip/hip_runtime.h>
#include <math.h>

// ChannelDropout: out[b,c,t] = x[b,c,t] * scale[b,c]
// scale = (valid && dist(pos, center0) > 0.1) ? 1/(prob_kept + 1e-8) : 0
// prob_kept = mean over centers 1..N-1 of (dist > 0.1)
// valid = !(pos == (-2,-2))
//
// v5 (A/B: v2 with PLAIN stores). Evidence so far: four structurally
// different kernels (row-block+barrier 95us, row-block nobarrier+nt 102us,
// split row-loop+nt 114us, split flat copy-shape ~105us) all sit in a
// 95-115us band vs the 67us ideal — consistent with the harness poison
// fill (845 MB > L3) leaving L2/L3 full of dirty lines that our stream
// must evict. Shape barely matters; the two live variables are the
// barrier prologue and the store mode. v5 isolates store mode: identical
// to v2 (loads-first, all-wave redundant scale, no barrier/LDS) except
// stores are plain (write-combine through L2 — the 6.5 TB/s fill path).

typedef float f32x4 __attribute__((ext_vector_type(4)));

__global__ __launch_bounds__(256) void ChannelDropout_14851996910142_kernel(
    const float* __restrict__ x,
    const float* __restrict__ pos,
    const float* __restrict__ centers,
    float* __restrict__ out,
    int ncenters, int tlen)
{
    const int row  = blockIdx.x;
    const int tid  = threadIdx.x;
    const int lane = tid & 63;

    const size_t base = (size_t)row * (size_t)tlen;
    const int t4 = tlen >> 2;                    // 750 float4 per row
    const f32x4* __restrict__ xr   = (const f32x4*)(x + base);
    f32x4* __restrict__       orow = (f32x4*)(out + base);

    // ---- issue the bulk HBM loads first (3 float4/thread covers t4<=768)
    const int i0 = tid, i1 = tid + 256, i2 = tid + 512;
    const bool p0 = i0 < t4, p1 = i1 < t4, p2 = i2 < t4;
    f32x4 v0 = {}, v1 = {}, v2 = {};
    if (p0) v0 = xr[i0];
    if (p1) v1 = xr[i1];
    if (p2) v2 = xr[i2];

    // ---- per-wave scale (uniform per row; redundant across the 4 waves)
    const float px = pos[2 * row];
    const float py = pos[2 * row + 1];
    const bool valid = !(px == -2.0f && py == -2.0f);

    float cnt = 0.0f;
    for (int c = 1 + lane; c < ncenters; c += 64) {
        const float dx = px - centers[2 * c];
        const float dy = py - centers[2 * c + 1];
        // match np: d = sqrt(dx*dx + dy*dy), no fma contraction
        const float d2 = __fadd_rn(__fmul_rn(dx, dx), __fmul_rn(dy, dy));
        cnt += (sqrtf(d2) > 0.1f) ? 1.0f : 0.0f;
    }
    // butterfly: ALL lanes end with the full sum (exact: integer-valued fp32)
    #pragma unroll
    for (int off = 32; off > 0; off >>= 1)
        cnt += __shfl_xor(cnt, off, 64);

    const float dx0 = px - centers[0];
    const float dy0 = py - centers[1];
    const float d02 = __fadd_rn(__fmul_rn(dx0, dx0), __fmul_rn(dy0, dy0));
    const bool kept0 = sqrtf(d02) > 0.1f;
    const int denom = (ncenters > 1) ? (ncenters - 1) : 1;
    const float prob = cnt / (float)denom;
    const float s = (valid && kept0) ? (1.0f / (prob + 1e-8f)) : 0.0f;

    // ---- scaled streaming stores (PLAIN: write-combine through L2)
    if (p0) orow[i0] = v0 * s;
    if (p1) orow[i1] = v1 * s;
    if (p2) orow[i2] = v2 * s;

    // generic tails (not taken for tlen = 3000)
    for (int i = tid + 768; i < t4; i += 256) {
        f32x4 v = xr[i];
        orow[i] = v * s;
    }
    for (int i = (t4 << 2) + tid; i < tlen; i += 256) {
        out[base + i] = x[base + i] * s;
    }
}

extern "C" void kernel_launch(void* const* d_in, const int* in_sizes, int n_in,
                              void* d_out, int out_size, void* d_ws, size_t ws_size,
                              hipStream_t stream) {
    const float* x       = (const float*)d_in[0];   // [B, C, T]
    const float* pos     = (const float*)d_in[1];   // [B, C, 2]
    const float* centers = (const float*)d_in[2];   // [N, 2]
    float* out = (float*)d_out;

    const int rows     = in_sizes[1] / 2;       // B*C = 17600
    const int tlen     = in_sizes[0] / rows;    // T = 3000
    const int ncenters = in_sizes[2] / 2;       // 101
    if (rows <= 0 || tlen <= 0) return;

    ChannelDropout_14851996910142_kernel<<<rows, 256, 0, stream>>>(
        x, pos, centers, out, ncenters, tlen);
}

// Round 7
// 345.354 us; speedup vs baseline: 1.0856x; 1.0113x over previous
//
#include <hip/hip_runtime.h>
#include <math.h>

// ChannelDropout: out[b,c,t] = x[b,c,t] * scale[b,c]
// scale = (valid && dist(pos, center0) > 0.1) ? 1/(prob_kept + 1e-8) : 0
// prob_kept = mean over centers 1..N-1 of (dist > 0.1)
// valid = !(pos == (-2,-2))
//
// v6 (A/B: v5 + NONTEMPORAL LOADS on the x stream, stores stay PLAIN).
// Ledger: v1 barrier+plain 95us | v2 nobar+nt-store 102 | v3 split+nt 114 |
// v4 split-flat+plain ~105 | v5 nobar+plain 93 (best, ties v1).
// Theory: the 845MB harness poison fill leaves ~288MB of dirty lines in
// L2+L3; every line WE allocate evicts one -> forced poison writeback
// inside our timed window (~250MB extra -> ~103us predicted, matches the
// 93-115 band). x is read-once: nt loads (gfx950 'nt' bit, stream/no-
// allocate) should halve the forced-writeback volume. Stores stay plain:
// nt stores measured +9us (v2 vs v5), and out's lines are the freshly
// poisoned dirty residents — plain stores overwrite them in place.

typedef float f32x4 __attribute__((ext_vector_type(4)));

__global__ __launch_bounds__(256) void ChannelDropout_14851996910142_kernel(
    const float* __restrict__ x,
    const float* __restrict__ pos,
    const float* __restrict__ centers,
    float* __restrict__ out,
    int ncenters, int tlen)
{
    const int row  = blockIdx.x;
    const int tid  = threadIdx.x;
    const int lane = tid & 63;

    const size_t base = (size_t)row * (size_t)tlen;
    const int t4 = tlen >> 2;                    // 750 float4 per row
    const f32x4* __restrict__ xr   = (const f32x4*)(x + base);
    f32x4* __restrict__       orow = (f32x4*)(out + base);

    // ---- issue the bulk HBM loads first (3 float4/thread covers t4<=768)
    // nontemporal: read-once stream, don't allocate/pollute L2+L3
    const int i0 = tid, i1 = tid + 256, i2 = tid + 512;
    const bool p0 = i0 < t4, p1 = i1 < t4, p2 = i2 < t4;
    f32x4 v0 = {}, v1 = {}, v2 = {};
    if (p0) v0 = __builtin_nontemporal_load(xr + i0);
    if (p1) v1 = __builtin_nontemporal_load(xr + i1);
    if (p2) v2 = __builtin_nontemporal_load(xr + i2);

    // ---- per-wave scale (uniform per row; redundant across the 4 waves)
    const float px = pos[2 * row];
    const float py = pos[2 * row + 1];
    const bool valid = !(px == -2.0f && py == -2.0f);

    float cnt = 0.0f;
    for (int c = 1 + lane; c < ncenters; c += 64) {
        const float dx = px - centers[2 * c];
        const float dy = py - centers[2 * c + 1];
        // match np: d = sqrt(dx*dx + dy*dy), no fma contraction
        const float d2 = __fadd_rn(__fmul_rn(dx, dx), __fmul_rn(dy, dy));
        cnt += (sqrtf(d2) > 0.1f) ? 1.0f : 0.0f;
    }
    // butterfly: ALL lanes end with the full sum (exact: integer-valued fp32)
    #pragma unroll
    for (int off = 32; off > 0; off >>= 1)
        cnt += __shfl_xor(cnt, off, 64);

    const float dx0 = px - centers[0];
    const float dy0 = py - centers[1];
    const float d02 = __fadd_rn(__fmul_rn(dx0, dx0), __fmul_rn(dy0, dy0));
    const bool kept0 = sqrtf(d02) > 0.1f;
    const int denom = (ncenters > 1) ? (ncenters - 1) : 1;
    const float prob = cnt / (float)denom;
    const float s = (valid && kept0) ? (1.0f / (prob + 1e-8f)) : 0.0f;

    // ---- scaled streaming stores (PLAIN: hit/overwrite resident lines)
    if (p0) orow[i0] = v0 * s;
    if (p1) orow[i1] = v1 * s;
    if (p2) orow[i2] = v2 * s;

    // generic tails (not taken for tlen = 3000)
    for (int i = tid + 768; i < t4; i += 256) {
        f32x4 v = __builtin_nontemporal_load(xr + i);
        orow[i] = v * s;
    }
    for (int i = (t4 << 2) + tid; i < tlen; i += 256) {
        out[base + i] = x[base + i] * s;
    }
}

extern "C" void kernel_launch(void* const* d_in, const int* in_sizes, int n_in,
                              void* d_out, int out_size, void* d_ws, size_t ws_size,
                              hipStream_t stream) {
    const float* x       = (const float*)d_in[0];   // [B, C, T]
    const float* pos     = (const float*)d_in[1];   // [B, C, 2]
    const float* centers = (const float*)d_in[2];   // [N, 2]
    float* out = (float*)d_out;

    const int rows     = in_sizes[1] / 2;       // B*C = 17600
    const int tlen     = in_sizes[0] / rows;    // T = 3000
    const int ncenters = in_sizes[2] / 2;       // 101
    if (rows <= 0 || tlen <= 0) return;

    ChannelDropout_14851996910142_kernel<<<rows, 256, 0, stream>>>(
        x, pos, centers, out, ncenters, tlen);
}